// Round 10
// baseline (2175.169 us; speedup 1.0000x reference)
//
#include <hip/hip_runtime.h>
#include <hip/hip_bf16.h>

#define DIM 128
typedef unsigned int u32;

// bf16x2 pack/unpack: low ushort = even feature, high = odd feature.
__device__ __forceinline__ u32 pack_bf16x2(float a, float b) {
    u32 ua = __float_as_uint(a), ub = __float_as_uint(b);
    ua = (ua + 0x7FFFu + ((ua >> 16) & 1u)) >> 16;        // RNE
    ub = (ub + 0x7FFFu + ((ub >> 16) & 1u)) >> 16;
    return ua | (ub << 16);
}
__device__ __forceinline__ float2 unpack_bf16x2(u32 h) {
    return make_float2(__uint_as_float(h << 16), __uint_as_float(h & 0xFFFF0000u));
}

// HW_REG_XCC_ID = 20 (gfx940+). If the id were wrong we'd just read some other
// register: slice = value&3 is still valid and the work queues keep correctness
// (only locality is lost).
__device__ __forceinline__ int get_xcc() {
    return (int)(__builtin_amdgcn_s_getreg((31u << 11) | 20) & 0xFu);
}

// ======================= init (replaces 4 memsets) =======================
// meta: [0]=total, [1..4]=qcur layer1, [5..8]=qcur layer2
__global__ void init_k(int* __restrict__ deg, int* __restrict__ meta,
                       float* __restrict__ sums, float* __restrict__ cnt,
                       int N, int G)
{
    int i = blockIdx.x * blockDim.x + threadIdx.x;
    if (i < N) deg[i] = 0;
    if (i < 9) meta[i] = 0;
    if (i < G) { sums[i] = 0.f; cnt[i] = 0.f; }
}

// ======================= CSR build =======================

__global__ void edge_count(int* __restrict__ deg, const int* __restrict__ dst, int E) {
    int e = blockIdx.x * blockDim.x + threadIdx.x;
    if (e < E) atomicAdd(&deg[dst[e]], 1);
}

// Bucket starts padded to multiples of 4; pad slots zeroed here (csr_nrm=0
// contributes nothing). Per-wave scan + one cursor atomic.
__global__ __launch_bounds__(256) void alloc_offsets(
    const int* __restrict__ deg, int* __restrict__ start, int* __restrict__ end_,
    int* __restrict__ cursor, float* __restrict__ dinv, int* __restrict__ total,
    int* __restrict__ csr_src, float* __restrict__ csr_nrm, int N)
{
    int i = blockIdx.x * blockDim.x + threadIdx.x;
    int lane = threadIdx.x & 63;
    int d  = (i < N) ? deg[i] : 0;
    int d4 = (d + 3) & ~3;
    int pre = d4;
    #pragma unroll
    for (int off = 1; off < 64; off <<= 1) {
        int v = __shfl_up(pre, off, 64);
        if (lane >= off) pre += v;
    }
    int waveTot = __shfl(pre, 63, 64);
    int base = 0;
    if (lane == 63) base = atomicAdd(total, waveTot);
    base = __shfl(base, 63, 64);
    if (i < N) {
        int st = base + pre - d4;
        start[i]  = st;
        end_[i]   = st + d;
        cursor[i] = st;
        dinv[i]   = rsqrtf((float)(d + 1));   // +1 self-loop
        for (int p = d; p < d4; ++p) {        // zero the <=3 pad slots
            csr_src[st + p] = 0;
            csr_nrm[st + p] = 0.f;
        }
    }
}

__global__ void scatter_edges(const int* __restrict__ src, const int* __restrict__ dst,
                              const float* __restrict__ dinv, int* __restrict__ cursor,
                              int* __restrict__ csr_src, float* __restrict__ csr_nrm, int E)
{
    int e = blockIdx.x * blockDim.x + threadIdx.x;
    if (e >= E) return;
    int s = src[e], d = dst[e];
    int p = atomicAdd(&cursor[d], 1);
    csr_src[p] = s;
    csr_nrm[p] = dinv[s] * dinv[d];
}

// ============ XCD-affine, feature-sliced gather (work queues) ============
// 4 slices x 32 feats (64 B). Block reads its XCC_ID; blocks on XCD x pull
// (chunk, slice x&3) tasks from that slice's atomic queue, then steal.
// Each XCD thus keeps ~one 3.2 MB H-slice L2-resident.
// Wave layout (r8-verified): one node at a time; e_off=lane>>4 (4 edges in
// parallel), d=lane&15 (dword within slice). 16 edges in flight per iter.
template<int FUSE_POOL>
__global__ __launch_bounds__(256) void gather_q(
    const u32* __restrict__ H, u32* __restrict__ O,
    const int* __restrict__ csr_src, const float* __restrict__ csr_nrm,
    const int* __restrict__ start, const int* __restrict__ end_,
    const float* __restrict__ dinv, int N, int nchunks, int* __restrict__ qcur,
    const float* __restrict__ b2, const float* __restrict__ wlin,
    const int* __restrict__ batch, float* __restrict__ sums, float* __restrict__ cnt)
{
    const int lane  = threadIdx.x & 63;
    const int e_off = lane >> 4;
    const int d     = lane & 15;
    const int myslice = get_xcc() & 3;

    for (int pass = 0; pass < 4; ++pass) {
        const int s = (myslice + pass) & 3;
        const u32* Hs = H + s * 16 + d;          // row stride 64 dwords
        for (;;) {
            int c;
            if (lane == 0) c = atomicAdd(&qcur[s], 1);
            c = __shfl(c, 0, 64);
            if (c >= nchunks) break;

            int nodeEnd = min((c + 1) * 4, N);
            for (int node = c * 4; node < nodeEnd; ++node) {
                int st = start[node], en = end_[node];
                int en_pad = st + ((en - st + 3) & ~3);

                float2 acc = {0.f, 0.f};
                int j = st;
                for (; j + 16 <= en_pad; j += 16) {
                    int   s0 = csr_src[j + e_off];
                    int   s1 = csr_src[j + 4 + e_off];
                    int   s2 = csr_src[j + 8 + e_off];
                    int   s3 = csr_src[j + 12 + e_off];
                    float n0 = csr_nrm[j + e_off];
                    float n1 = csr_nrm[j + 4 + e_off];
                    float n2 = csr_nrm[j + 8 + e_off];
                    float n3 = csr_nrm[j + 12 + e_off];
                    u32 r0 = Hs[(size_t)s0 * 64];
                    u32 r1 = Hs[(size_t)s1 * 64];
                    u32 r2 = Hs[(size_t)s2 * 64];
                    u32 r3 = Hs[(size_t)s3 * 64];
                    float2 h0 = unpack_bf16x2(r0), h1 = unpack_bf16x2(r1);
                    float2 h2 = unpack_bf16x2(r2), h3 = unpack_bf16x2(r3);
                    acc.x = fmaf(h0.x, n0, acc.x);  acc.y = fmaf(h0.y, n0, acc.y);
                    acc.x = fmaf(h1.x, n1, acc.x);  acc.y = fmaf(h1.y, n1, acc.y);
                    acc.x = fmaf(h2.x, n2, acc.x);  acc.y = fmaf(h2.y, n2, acc.y);
                    acc.x = fmaf(h3.x, n3, acc.x);  acc.y = fmaf(h3.y, n3, acc.y);
                }
                for (; j + 4 <= en_pad; j += 4) {
                    int   s0 = csr_src[j + e_off];
                    float n0 = csr_nrm[j + e_off];
                    float2 h0 = unpack_bf16x2(Hs[(size_t)s0 * 64]);
                    acc.x = fmaf(h0.x, n0, acc.x);
                    acc.y = fmaf(h0.y, n0, acc.y);
                }

                // reduce across the 4 e_off groups
                acc.x += __shfl_xor(acc.x, 16, 64);
                acc.y += __shfl_xor(acc.y, 16, 64);
                acc.x += __shfl_xor(acc.x, 32, 64);
                acc.y += __shfl_xor(acc.y, 32, 64);

                // self-loop (post-reduce)
                float di = dinv[node];
                float nn = di * di;
                float2 self = unpack_bf16x2(Hs[(size_t)node * 64]);
                float2 res = make_float2(fmaf(self.x, nn, acc.x),
                                         fmaf(self.y, nn, acc.y));

                if (FUSE_POOL) {
                    int f = s * 32 + 2 * d;
                    float v = fmaxf(res.x + b2[f], 0.f)     * wlin[f]
                            + fmaxf(res.y + b2[f + 1], 0.f) * wlin[f + 1];
                    #pragma unroll
                    for (int m = 1; m <= 8; m <<= 1) v += __shfl_xor(v, m, 64);
                    if (lane == 0) {
                        int g = batch[node];
                        unsafeAtomicAdd(&sums[g], v);
                        if (s == 0) unsafeAtomicAdd(&cnt[g], 1.0f);
                    }
                } else {
                    if (lane < 16)
                        O[(size_t)node * 64 + s * 16 + d] = pack_bf16x2(res.x, res.y);
                }
            }
        }
    }
}

// ======================= GEMM =======================
// Y[node][f] = sum_k X'[node][k] * W[k][f]; W fp32; Y bf16.
// MODE 0: X fp32 (the raw input x). MODE 1: X bf16 + bias + relu.
// BM=64 x BN=128 x BK=32 LDS outer product; thread tile 8 nodes x 4 feats.

template<int MODE>
__global__ __launch_bounds__(256) void gemm_nodes(
    const void* __restrict__ Xv,
    const float* __restrict__ bias,
    const float* __restrict__ W,   // [128][128] row-major (k, f)
    u32* __restrict__ Y, int N)
{
    __shared__ float As[32][72];
    __shared__ float Bs[32][132];
    const int t = threadIdx.x;
    const int node0 = blockIdx.x * 64;
    const int tx = t & 31;
    const int ty = t >> 5;
    const int f0 = tx * 4;
    const int n0 = ty * 8;

    float acc[8][4];
    #pragma unroll
    for (int i = 0; i < 8; ++i)
        #pragma unroll
        for (int j = 0; j < 4; ++j) acc[i][j] = 0.f;

    const int sr  = t >> 3;
    const int sc4 = (t & 7) * 4;

    for (int k0 = 0; k0 < DIM; k0 += 32) {
        #pragma unroll
        for (int half = 0; half < 2; ++half) {
            int r = sr + half * 32;
            int node = node0 + r;
            float v[4] = {0.f, 0.f, 0.f, 0.f};
            if (node < N) {
                if (MODE == 0) {
                    const float* X = (const float*)Xv;
                    *(float4*)v = *(const float4*)&X[(size_t)node * DIM + k0 + sc4];
                } else {
                    const u32* X = (const u32*)Xv;
                    uint2 q = *(const uint2*)&X[(size_t)node * 64 + (k0 + sc4) / 2];
                    float2 ab = unpack_bf16x2(q.x);
                    float2 cd = unpack_bf16x2(q.y);
                    v[0] = ab.x; v[1] = ab.y; v[2] = cd.x; v[3] = cd.y;
                }
            }
            if (MODE == 1) {
                float bv[4];
                *(float4*)bv = *(const float4*)&bias[k0 + sc4];
                #pragma unroll
                for (int i = 0; i < 4; ++i) v[i] = fmaxf(v[i] + bv[i], 0.f);
                if (node >= N) { v[0]=v[1]=v[2]=v[3]=0.f; }
            }
            #pragma unroll
            for (int i = 0; i < 4; ++i) As[sc4 + i][r] = v[i];
        }
        #pragma unroll
        for (int i = 0; i < 4; ++i) {
            int kk = (t >> 5) + i * 8;
            float4 wv = *(const float4*)&W[(size_t)(k0 + kk) * DIM + f0];
            *(float4*)&Bs[kk][f0] = wv;
        }
        __syncthreads();

        #pragma unroll 4
        for (int kk = 0; kk < 32; ++kk) {
            float4 a0 = *(const float4*)&As[kk][n0];
            float4 a1 = *(const float4*)&As[kk][n0 + 4];
            float4 b  = *(const float4*)&Bs[kk][f0];
            float av[8] = {a0.x,a0.y,a0.z,a0.w,a1.x,a1.y,a1.z,a1.w};
            float bv[4] = {b.x,b.y,b.z,b.w};
            #pragma unroll
            for (int i = 0; i < 8; ++i)
                #pragma unroll
                for (int j = 0; j < 4; ++j)
                    acc[i][j] = fmaf(av[i], bv[j], acc[i][j]);
        }
        __syncthreads();
    }

    #pragma unroll
    for (int i = 0; i < 8; ++i) {
        int node = node0 + n0 + i;
        if (node < N) {
            uint2 o;
            o.x = pack_bf16x2(acc[i][0], acc[i][1]);
            o.y = pack_bf16x2(acc[i][2], acc[i][3]);
            *(uint2*)&Y[(size_t)node * 64 + f0 / 2] = o;
        }
    }
}

__global__ void final_kernel(const float* __restrict__ sums,
                             const float* __restrict__ cnt,
                             const float* __restrict__ blin,
                             float* __restrict__ out, int G)
{
    int g = blockIdx.x * blockDim.x + threadIdx.x;
    if (g < G) out[g] = sums[g] / fmaxf(cnt[g], 1.0f) + blin[0];
}

// ======================= launch =======================

extern "C" void kernel_launch(void* const* d_in, const int* in_sizes, int n_in,
                              void* d_out, int out_size, void* d_ws, size_t ws_size,
                              hipStream_t stream)
{
    const float* x    = (const float*)d_in[0];
    const int*   src  = (const int*)d_in[1];
    const int*   dst  = (const int*)d_in[2];
    const int*   batch= (const int*)d_in[3];
    const float* W1   = (const float*)d_in[5];
    const float* b1   = (const float*)d_in[6];
    const float* W2   = (const float*)d_in[7];
    const float* b2   = (const float*)d_in[8];
    const float* wlin = (const float*)d_in[9];
    const float* blin = (const float*)d_in[10];
    float* out = (float*)d_out;

    const int N = in_sizes[0] / DIM;
    const int E = in_sizes[1];
    const int G = out_size;
    const size_t E_pad = (size_t)E + 4 * (size_t)N;   // per-bucket pad to x4

    // layout: B0(bf16 N*64 u32), B1, dinv(N), sums(G), cnt(G),
    //         deg/cursor(N), start(N), end(N), csr_src(E_pad), csr_nrm(E_pad),
    //         meta(9): total + qcur1[4] + qcur2[4]
    u32*   B0    = (u32*)d_ws;
    u32*   B1    = B0 + (size_t)N * 64;
    float* dinv  = (float*)(B1 + (size_t)N * 64);
    float* sums  = dinv + N;
    float* cnt   = sums + G;
    int*   deg_c = (int*)(cnt + G);
    int*   start = deg_c + N;
    int*   end_  = start + N;
    int*   csrs  = end_ + N;
    float* csrn  = (float*)(csrs + E_pad);
    int*   meta  = (int*)(csrn + E_pad);
    int*   total = meta;
    int*   qcur1 = meta + 1;
    int*   qcur2 = meta + 5;
    size_t need_bytes = ((size_t)(meta + 9) - (size_t)d_ws);
    if (ws_size < need_bytes) return;   // not expected: ws has always sufficed

    const int gblocks = (N + 63) / 64;
    const int eblocks = (E + 255) / 256;
    const int nchunks = (N + 3) / 4;

    // ---- init + CSR build (once, reused by both layers) ----
    init_k<<<(N + 255) / 256, 256, 0, stream>>>(deg_c, meta, sums, cnt, N, G);
    edge_count<<<eblocks, 256, 0, stream>>>(deg_c, dst, E);
    alloc_offsets<<<(N + 255) / 256, 256, 0, stream>>>(deg_c, start, end_, deg_c,
                                                       dinv, total, csrs, csrn, N);
    scatter_edges<<<eblocks, 256, 0, stream>>>(src, dst, dinv, deg_c, csrs, csrn, E);

    // ---- layer 1 ----
    gemm_nodes<0><<<gblocks, 256, 0, stream>>>(x, nullptr, W1, B0, N);
    gather_q<0><<<2048, 256, 0, stream>>>(B0, B1, csrs, csrn, start, end_,
                                          dinv, N, nchunks, qcur1,
                                          nullptr, nullptr, nullptr, nullptr, nullptr);
    // ---- layer 2 (gather fused with pooling) ----
    gemm_nodes<1><<<gblocks, 256, 0, stream>>>(B1, b1, W2, B0, N);
    gather_q<1><<<2048, 256, 0, stream>>>(B0, nullptr, csrs, csrn, start, end_,
                                          dinv, N, nchunks, qcur2,
                                          b2, wlin, batch, sums, cnt);
    final_kernel<<<(G + 255) / 256, 256, 0, stream>>>(sums, cnt, blin, out, G);
}

// Round 11
// 328.946 us; speedup vs baseline: 6.6125x; 6.6125x over previous
//
#include <hip/hip_runtime.h>
#include <hip/hip_bf16.h>

#define DIM 128
typedef unsigned int u32;

// bf16x2 pack/unpack: low ushort = even feature, high = odd feature.
__device__ __forceinline__ u32 pack_bf16x2(float a, float b) {
    u32 ua = __float_as_uint(a), ub = __float_as_uint(b);
    ua = (ua + 0x7FFFu + ((ua >> 16) & 1u)) >> 16;        // RNE
    ub = (ub + 0x7FFFu + ((ub >> 16) & 1u)) >> 16;
    return ua | (ub << 16);
}
__device__ __forceinline__ float2 unpack_bf16x2(u32 h) {
    return make_float2(__uint_as_float(h << 16), __uint_as_float(h & 0xFFFF0000u));
}

__device__ __forceinline__ void accum8(float* acc, uint4 r, float n) {
    float2 p0 = unpack_bf16x2(r.x), p1 = unpack_bf16x2(r.y);
    float2 p2 = unpack_bf16x2(r.z), p3 = unpack_bf16x2(r.w);
    acc[0] = fmaf(p0.x, n, acc[0]); acc[1] = fmaf(p0.y, n, acc[1]);
    acc[2] = fmaf(p1.x, n, acc[2]); acc[3] = fmaf(p1.y, n, acc[3]);
    acc[4] = fmaf(p2.x, n, acc[4]); acc[5] = fmaf(p2.y, n, acc[5]);
    acc[6] = fmaf(p3.x, n, acc[6]); acc[7] = fmaf(p3.y, n, acc[7]);
}

// ======================= init (replaces 4 memsets) =======================
__global__ void init_k(int* __restrict__ deg, int* __restrict__ total,
                       float* __restrict__ sums, float* __restrict__ cnt,
                       int N, int G)
{
    int i = blockIdx.x * blockDim.x + threadIdx.x;
    if (i < N) deg[i] = 0;
    if (i == 0) *total = 0;
    if (i < G) { sums[i] = 0.f; cnt[i] = 0.f; }
}

// ======================= GEMM device body =======================
// Y[node][f] = sum_k X'[node][k] * W[k][f]; W fp32; Y bf16.
// MODE 0: X fp32 (raw input x). MODE 1: X bf16 + bias + relu.
// BM=64 x BN=128 x BK=32 LDS outer product; thread tile 8 nodes x 4 feats.

template<int MODE>
__device__ __forceinline__ void gemm_body(
    const void* __restrict__ Xv, const float* __restrict__ bias,
    const float* __restrict__ W, u32* __restrict__ Y, int N, int block)
{
    __shared__ float As[32][72];
    __shared__ float Bs[32][132];
    const int t = threadIdx.x;
    const int node0 = block * 64;
    const int tx = t & 31;
    const int ty = t >> 5;
    const int f0 = tx * 4;
    const int n0 = ty * 8;

    float acc[8][4];
    #pragma unroll
    for (int i = 0; i < 8; ++i)
        #pragma unroll
        for (int j = 0; j < 4; ++j) acc[i][j] = 0.f;

    const int sr  = t >> 3;
    const int sc4 = (t & 7) * 4;

    for (int k0 = 0; k0 < DIM; k0 += 32) {
        #pragma unroll
        for (int half = 0; half < 2; ++half) {
            int r = sr + half * 32;
            int node = node0 + r;
            float v[4] = {0.f, 0.f, 0.f, 0.f};
            if (node < N) {
                if (MODE == 0) {
                    const float* X = (const float*)Xv;
                    *(float4*)v = *(const float4*)&X[(size_t)node * DIM + k0 + sc4];
                } else {
                    const u32* X = (const u32*)Xv;
                    uint2 q = *(const uint2*)&X[(size_t)node * 64 + (k0 + sc4) / 2];
                    float2 ab = unpack_bf16x2(q.x);
                    float2 cd = unpack_bf16x2(q.y);
                    v[0] = ab.x; v[1] = ab.y; v[2] = cd.x; v[3] = cd.y;
                }
            }
            if (MODE == 1) {
                float bv[4];
                *(float4*)bv = *(const float4*)&bias[k0 + sc4];
                #pragma unroll
                for (int i = 0; i < 4; ++i) v[i] = fmaxf(v[i] + bv[i], 0.f);
                if (node >= N) { v[0]=v[1]=v[2]=v[3]=0.f; }
            }
            #pragma unroll
            for (int i = 0; i < 4; ++i) As[sc4 + i][r] = v[i];
        }
        #pragma unroll
        for (int i = 0; i < 4; ++i) {
            int kk = (t >> 5) + i * 8;
            float4 wv = *(const float4*)&W[(size_t)(k0 + kk) * DIM + f0];
            *(float4*)&Bs[kk][f0] = wv;
        }
        __syncthreads();

        #pragma unroll 4
        for (int kk = 0; kk < 32; ++kk) {
            float4 a0 = *(const float4*)&As[kk][n0];
            float4 a1 = *(const float4*)&As[kk][n0 + 4];
            float4 b  = *(const float4*)&Bs[kk][f0];
            float av[8] = {a0.x,a0.y,a0.z,a0.w,a1.x,a1.y,a1.z,a1.w};
            float bv[4] = {b.x,b.y,b.z,b.w};
            #pragma unroll
            for (int i = 0; i < 8; ++i)
                #pragma unroll
                for (int j = 0; j < 4; ++j)
                    acc[i][j] = fmaf(av[i], bv[j], acc[i][j]);
        }
        __syncthreads();
    }

    #pragma unroll
    for (int i = 0; i < 8; ++i) {
        int node = node0 + n0 + i;
        if (node < N) {
            uint2 o;
            o.x = pack_bf16x2(acc[i][0], acc[i][1]);
            o.y = pack_bf16x2(acc[i][2], acc[i][3]);
            *(uint2*)&Y[(size_t)node * 64 + f0 / 2] = o;
        }
    }
}

// Fused: blocks [0,gblocks) run gemm1 (fp32 x @ W1 -> bf16 B0);
// blocks [gblocks, gblocks+eblocks) run edge_count (independent work).
__global__ __launch_bounds__(256) void gemm1_count(
    const float* __restrict__ x, const float* __restrict__ W1,
    u32* __restrict__ Y, int N, int gblocks,
    int* __restrict__ deg, const int* __restrict__ dst, int E)
{
    if ((int)blockIdx.x < gblocks) {
        gemm_body<0>(x, nullptr, W1, Y, N, blockIdx.x);
    } else {
        int e = ((int)blockIdx.x - gblocks) * 256 + threadIdx.x;
        if (e < E) atomicAdd(&deg[dst[e]], 1);
    }
}

__global__ __launch_bounds__(256) void gemm_nodes1(
    const u32* __restrict__ X, const float* __restrict__ bias,
    const float* __restrict__ W, u32* __restrict__ Y, int N)
{
    gemm_body<1>(X, bias, W, Y, N, blockIdx.x);
}

// ======================= CSR build =======================
// Bucket starts padded to multiples of 4; pad slots zeroed here (csr_nrm=0
// contributes nothing). Per-wave scan + one cursor atomic.
__global__ __launch_bounds__(256) void alloc_offsets(
    const int* __restrict__ deg, int* __restrict__ start, int* __restrict__ end_,
    int* __restrict__ cursor, float* __restrict__ dinv, int* __restrict__ total,
    int* __restrict__ csr_src, float* __restrict__ csr_nrm, int N)
{
    int i = blockIdx.x * blockDim.x + threadIdx.x;
    int lane = threadIdx.x & 63;
    int d  = (i < N) ? deg[i] : 0;
    int d4 = (d + 3) & ~3;
    int pre = d4;
    #pragma unroll
    for (int off = 1; off < 64; off <<= 1) {
        int v = __shfl_up(pre, off, 64);
        if (lane >= off) pre += v;
    }
    int waveTot = __shfl(pre, 63, 64);
    int base = 0;
    if (lane == 63) base = atomicAdd(total, waveTot);
    base = __shfl(base, 63, 64);
    if (i < N) {
        int st = base + pre - d4;
        start[i]  = st;
        end_[i]   = st + d;
        cursor[i] = st;
        dinv[i]   = rsqrtf((float)(d + 1));   // +1 self-loop
        for (int p = d; p < d4; ++p) {        // zero the <=3 pad slots
            csr_src[st + p] = 0;
            csr_nrm[st + p] = 0.f;
        }
    }
}

__global__ void scatter_edges(const int* __restrict__ src, const int* __restrict__ dst,
                              const float* __restrict__ dinv, int* __restrict__ cursor,
                              int* __restrict__ csr_src, float* __restrict__ csr_nrm, int E)
{
    int e = blockIdx.x * blockDim.x + threadIdx.x;
    if (e >= E) return;
    int s = src[e], d = dst[e];
    int p = atomicAdd(&cursor[d], 1);
    csr_src[p] = s;
    csr_nrm[p] = dinv[s] * dinv[d];
}

// ======================= gather aggregation (4 nodes / wave) ==============
// 16 lanes per node; lane gl holds dwords 4gl..4gl+3 (features 8gl..8gl+7).
// One wave row-load instruction covers 4 rows x 256 B = 1 KB (16 B/lane).
// Bucket lengths are multiples of 4 -> inner loop has no scalar tail.
template<int FUSE_POOL>
__global__ __launch_bounds__(256) void gather4(
    const u32* __restrict__ H, u32* __restrict__ O,
    const int* __restrict__ csr_src, const float* __restrict__ csr_nrm,
    const int* __restrict__ start, const int* __restrict__ end_,
    const float* __restrict__ dinv, int N,
    const float* __restrict__ b2, const float* __restrict__ wlin,
    const int* __restrict__ batch, float* __restrict__ sums, float* __restrict__ cnt)
{
    const int grp  = threadIdx.x >> 4;          // 0..15
    const int gl   = threadIdx.x & 15;          // lane within group
    const int node = blockIdx.x * 16 + grp;
    if (node >= N) return;

    const u32* Hl = H + gl * 4;                 // row stride 64 dwords

    int st = start[node], en = end_[node];
    int en_pad = st + ((en - st + 3) & ~3);

    float acc[8] = {0.f,0.f,0.f,0.f,0.f,0.f,0.f,0.f};

    int j = st;
    for (; j + 8 <= en_pad; j += 8) {
        int4   sa = *(const int4*)  &csr_src[j];
        int4   sb = *(const int4*)  &csr_src[j + 4];
        float4 na = *(const float4*)&csr_nrm[j];
        float4 nb = *(const float4*)&csr_nrm[j + 4];
        uint4 r0 = *(const uint4*)&Hl[(size_t)sa.x * 64];
        uint4 r1 = *(const uint4*)&Hl[(size_t)sa.y * 64];
        uint4 r2 = *(const uint4*)&Hl[(size_t)sa.z * 64];
        uint4 r3 = *(const uint4*)&Hl[(size_t)sa.w * 64];
        uint4 r4 = *(const uint4*)&Hl[(size_t)sb.x * 64];
        uint4 r5 = *(const uint4*)&Hl[(size_t)sb.y * 64];
        uint4 r6 = *(const uint4*)&Hl[(size_t)sb.z * 64];
        uint4 r7 = *(const uint4*)&Hl[(size_t)sb.w * 64];
        accum8(acc, r0, na.x);  accum8(acc, r1, na.y);
        accum8(acc, r2, na.z);  accum8(acc, r3, na.w);
        accum8(acc, r4, nb.x);  accum8(acc, r5, nb.y);
        accum8(acc, r6, nb.z);  accum8(acc, r7, nb.w);
    }
    if (j < en_pad) {   // exactly one 4-chunk
        int4   sa = *(const int4*)  &csr_src[j];
        float4 na = *(const float4*)&csr_nrm[j];
        uint4 r0 = *(const uint4*)&Hl[(size_t)sa.x * 64];
        uint4 r1 = *(const uint4*)&Hl[(size_t)sa.y * 64];
        uint4 r2 = *(const uint4*)&Hl[(size_t)sa.z * 64];
        uint4 r3 = *(const uint4*)&Hl[(size_t)sa.w * 64];
        accum8(acc, r0, na.x);  accum8(acc, r1, na.y);
        accum8(acc, r2, na.z);  accum8(acc, r3, na.w);
    }

    // self-loop
    float di = dinv[node];
    uint4 rs = *(const uint4*)&Hl[(size_t)node * 64];
    accum8(acc, rs, di * di);

    if (FUSE_POOL) {
        int f0 = gl * 8;
        float v = 0.f;
        #pragma unroll
        for (int i = 0; i < 8; ++i)
            v += fmaxf(acc[i] + b2[f0 + i], 0.f) * wlin[f0 + i];
        #pragma unroll
        for (int m = 1; m <= 8; m <<= 1) v += __shfl_xor(v, m, 64); // within group
        if (gl == 0) {
            int g = batch[node];
            unsafeAtomicAdd(&sums[g], v);
            unsafeAtomicAdd(&cnt[g], 1.0f);
        }
    } else {
        uint4 o;
        o.x = pack_bf16x2(acc[0], acc[1]);
        o.y = pack_bf16x2(acc[2], acc[3]);
        o.z = pack_bf16x2(acc[4], acc[5]);
        o.w = pack_bf16x2(acc[6], acc[7]);
        *(uint4*)&O[(size_t)node * 64 + gl * 4] = o;
    }
}

__global__ void final_kernel(const float* __restrict__ sums,
                             const float* __restrict__ cnt,
                             const float* __restrict__ blin,
                             float* __restrict__ out, int G)
{
    int g = blockIdx.x * blockDim.x + threadIdx.x;
    if (g < G) out[g] = sums[g] / fmaxf(cnt[g], 1.0f) + blin[0];
}

// ======================= launch =======================

extern "C" void kernel_launch(void* const* d_in, const int* in_sizes, int n_in,
                              void* d_out, int out_size, void* d_ws, size_t ws_size,
                              hipStream_t stream)
{
    const float* x    = (const float*)d_in[0];
    const int*   src  = (const int*)d_in[1];
    const int*   dst  = (const int*)d_in[2];
    const int*   batch= (const int*)d_in[3];
    const float* W1   = (const float*)d_in[5];
    const float* b1   = (const float*)d_in[6];
    const float* W2   = (const float*)d_in[7];
    const float* b2   = (const float*)d_in[8];
    const float* wlin = (const float*)d_in[9];
    const float* blin = (const float*)d_in[10];
    float* out = (float*)d_out;

    const int N = in_sizes[0] / DIM;
    const int E = in_sizes[1];
    const int G = out_size;
    const size_t E_pad = (size_t)E + 4 * (size_t)N;   // per-bucket pad to x4

    // layout: B0(bf16 N*64 u32), B1, dinv(N), sums(G), cnt(G),
    //         deg/cursor(N), start(N), end(N), csr_src(E_pad), csr_nrm(E_pad), total
    u32*   B0    = (u32*)d_ws;
    u32*   B1    = B0 + (size_t)N * 64;
    float* dinv  = (float*)(B1 + (size_t)N * 64);
    float* sums  = dinv + N;
    float* cnt   = sums + G;
    int*   deg_c = (int*)(cnt + G);
    int*   start = deg_c + N;
    int*   end_  = start + N;
    int*   csrs  = end_ + N;
    float* csrn  = (float*)(csrs + E_pad);
    int*   total = (int*)(csrn + E_pad);
    size_t need_bytes = ((size_t)(total + 1) - (size_t)d_ws);
    if (ws_size < need_bytes) return;   // not expected: ws has always sufficed

    const int gblocks = (N + 63) / 64;
    const int eblocks = (E + 255) / 256;
    const int g4blocks = (N + 15) / 16;

    // ---- init, then gemm1 fused with edge_count (independent work) ----
    init_k<<<(N + 255) / 256, 256, 0, stream>>>(deg_c, total, sums, cnt, N, G);
    gemm1_count<<<gblocks + eblocks, 256, 0, stream>>>(x, W1, B0, N, gblocks,
                                                       deg_c, dst, E);
    alloc_offsets<<<(N + 255) / 256, 256, 0, stream>>>(deg_c, start, end_, deg_c,
                                                       dinv, total, csrs, csrn, N);
    scatter_edges<<<eblocks, 256, 0, stream>>>(src, dst, dinv, deg_c, csrs, csrn, E);

    // ---- layer 1 aggregation ----
    gather4<0><<<g4blocks, 256, 0, stream>>>(B0, B1, csrs, csrn, start, end_,
                                             dinv, N, nullptr, nullptr,
                                             nullptr, nullptr, nullptr);
    // ---- layer 2 (gather fused with pooling) ----
    gemm_nodes1<<<gblocks, 256, 0, stream>>>(B1, b1, W2, B0, N);
    gather4<1><<<g4blocks, 256, 0, stream>>>(B0, nullptr, csrs, csrn, start,
                                             end_, dinv, N, b2, wlin,
                                             batch, sums, cnt);
    final_kernel<<<(G + 255) / 256, 256, 0, stream>>>(sums, cnt, blin, out, G);
}

// Round 12
// 323.395 us; speedup vs baseline: 6.7260x; 1.0172x over previous
//
#include <hip/hip_runtime.h>
#include <hip/hip_bf16.h>

#define DIM 128
typedef unsigned int u32;

// bf16x2 pack/unpack: low ushort = even feature, high = odd feature.
__device__ __forceinline__ u32 pack_bf16x2(float a, float b) {
    u32 ua = __float_as_uint(a), ub = __float_as_uint(b);
    ua = (ua + 0x7FFFu + ((ua >> 16) & 1u)) >> 16;        // RNE
    ub = (ub + 0x7FFFu + ((ub >> 16) & 1u)) >> 16;
    return ua | (ub << 16);
}
__device__ __forceinline__ ushort bf16_of(float a) {
    u32 ua = __float_as_uint(a);
    return (ushort)((ua + 0x7FFFu + ((ua >> 16) & 1u)) >> 16);
}
__device__ __forceinline__ float f_of_bf16(ushort h) {
    return __uint_as_float(((u32)h) << 16);
}
__device__ __forceinline__ float2 unpack_bf16x2(u32 h) {
    return make_float2(__uint_as_float(h << 16), __uint_as_float(h & 0xFFFF0000u));
}

__device__ __forceinline__ void accum8(float* acc, uint4 r, float n) {
    float2 p0 = unpack_bf16x2(r.x), p1 = unpack_bf16x2(r.y);
    float2 p2 = unpack_bf16x2(r.z), p3 = unpack_bf16x2(r.w);
    acc[0] = fmaf(p0.x, n, acc[0]); acc[1] = fmaf(p0.y, n, acc[1]);
    acc[2] = fmaf(p1.x, n, acc[2]); acc[3] = fmaf(p1.y, n, acc[3]);
    acc[4] = fmaf(p2.x, n, acc[4]); acc[5] = fmaf(p2.y, n, acc[5]);
    acc[6] = fmaf(p3.x, n, acc[6]); acc[7] = fmaf(p3.y, n, acc[7]);
}

// ======================= init (replaces 4 memsets) =======================
__global__ void init_k(int* __restrict__ deg, int* __restrict__ total,
                       float* __restrict__ sums, float* __restrict__ cnt,
                       int N, int G)
{
    int i = blockIdx.x * blockDim.x + threadIdx.x;
    if (i < N) deg[i] = 0;
    if (i == 0) *total = 0;
    if (i < G) { sums[i] = 0.f; cnt[i] = 0.f; }
}

// ======================= GEMM1 (+edge_count fused) =======================
// Y[node][f] = sum_k X[node][k] * W[k][f]; X fp32, W fp32, Y bf16.
// BM=64 x BN=128 x BK=32 LDS outer product; thread tile 8 nodes x 4 feats.

__device__ __forceinline__ void gemm_body0(
    const float* __restrict__ X, const float* __restrict__ W,
    u32* __restrict__ Y, int N, int block)
{
    __shared__ float As[32][72];
    __shared__ float Bs[32][132];
    const int t = threadIdx.x;
    const int node0 = block * 64;
    const int tx = t & 31;
    const int ty = t >> 5;
    const int f0 = tx * 4;
    const int n0 = ty * 8;

    float acc[8][4];
    #pragma unroll
    for (int i = 0; i < 8; ++i)
        #pragma unroll
        for (int j = 0; j < 4; ++j) acc[i][j] = 0.f;

    const int sr  = t >> 3;
    const int sc4 = (t & 7) * 4;

    for (int k0 = 0; k0 < DIM; k0 += 32) {
        #pragma unroll
        for (int half = 0; half < 2; ++half) {
            int r = sr + half * 32;
            int node = node0 + r;
            float v[4] = {0.f, 0.f, 0.f, 0.f};
            if (node < N)
                *(float4*)v = *(const float4*)&X[(size_t)node * DIM + k0 + sc4];
            #pragma unroll
            for (int i = 0; i < 4; ++i) As[sc4 + i][r] = v[i];
        }
        #pragma unroll
        for (int i = 0; i < 4; ++i) {
            int kk = (t >> 5) + i * 8;
            float4 wv = *(const float4*)&W[(size_t)(k0 + kk) * DIM + f0];
            *(float4*)&Bs[kk][f0] = wv;
        }
        __syncthreads();

        #pragma unroll 4
        for (int kk = 0; kk < 32; ++kk) {
            float4 a0 = *(const float4*)&As[kk][n0];
            float4 a1 = *(const float4*)&As[kk][n0 + 4];
            float4 b  = *(const float4*)&Bs[kk][f0];
            float av[8] = {a0.x,a0.y,a0.z,a0.w,a1.x,a1.y,a1.z,a1.w};
            float bv[4] = {b.x,b.y,b.z,b.w};
            #pragma unroll
            for (int i = 0; i < 8; ++i)
                #pragma unroll
                for (int j = 0; j < 4; ++j)
                    acc[i][j] = fmaf(av[i], bv[j], acc[i][j]);
        }
        __syncthreads();
    }

    #pragma unroll
    for (int i = 0; i < 8; ++i) {
        int node = node0 + n0 + i;
        if (node < N) {
            uint2 o;
            o.x = pack_bf16x2(acc[i][0], acc[i][1]);
            o.y = pack_bf16x2(acc[i][2], acc[i][3]);
            *(uint2*)&Y[(size_t)node * 64 + f0 / 2] = o;
        }
    }
}

__global__ __launch_bounds__(256) void gemm1_count(
    const float* __restrict__ x, const float* __restrict__ W1,
    u32* __restrict__ Y, int N, int gblocks,
    int* __restrict__ deg, const int* __restrict__ dst, int E)
{
    if ((int)blockIdx.x < gblocks) {
        gemm_body0(x, W1, Y, N, blockIdx.x);
    } else {
        int e = ((int)blockIdx.x - gblocks) * 256 + threadIdx.x;
        if (e < E) atomicAdd(&deg[dst[e]], 1);
    }
}

// ======================= CSR build =======================
__global__ __launch_bounds__(256) void alloc_offsets(
    const int* __restrict__ deg, int* __restrict__ start, int* __restrict__ end_,
    int* __restrict__ cursor, float* __restrict__ dinv, int* __restrict__ total,
    int* __restrict__ csr_src, float* __restrict__ csr_nrm, int N)
{
    int i = blockIdx.x * blockDim.x + threadIdx.x;
    int lane = threadIdx.x & 63;
    int d  = (i < N) ? deg[i] : 0;
    int d4 = (d + 3) & ~3;
    int pre = d4;
    #pragma unroll
    for (int off = 1; off < 64; off <<= 1) {
        int v = __shfl_up(pre, off, 64);
        if (lane >= off) pre += v;
    }
    int waveTot = __shfl(pre, 63, 64);
    int base = 0;
    if (lane == 63) base = atomicAdd(total, waveTot);
    base = __shfl(base, 63, 64);
    if (i < N) {
        int st = base + pre - d4;
        start[i]  = st;
        end_[i]   = st + d;
        cursor[i] = st;
        dinv[i]   = rsqrtf((float)(d + 1));   // +1 self-loop
        for (int p = d; p < d4; ++p) {        // zero the <=3 pad slots
            csr_src[st + p] = 0;
            csr_nrm[st + p] = 0.f;
        }
    }
}

__global__ void scatter_edges(const int* __restrict__ src, const int* __restrict__ dst,
                              const float* __restrict__ dinv, int* __restrict__ cursor,
                              int* __restrict__ csr_src, float* __restrict__ csr_nrm, int E)
{
    int e = blockIdx.x * blockDim.x + threadIdx.x;
    if (e >= E) return;
    int s = src[e], d = dst[e];
    int p = atomicAdd(&cursor[d], 1);
    csr_src[p] = s;
    csr_nrm[p] = dinv[s] * dinv[d];
}

// ======================= gather core (4 nodes / wave) =====================
// 16 lanes per node; lane gl holds dwords 4gl..4gl+3 (features 8gl..8gl+7).
// One wave row-load instruction covers 4 rows x 256 B = 1 KB (16 B/lane).
__device__ __forceinline__ void gather_core(
    const u32* __restrict__ Hl, const int* __restrict__ csr_src,
    const float* __restrict__ csr_nrm, const float* __restrict__ dinv,
    int node, int st, int en, float* acc)
{
    int en_pad = st + ((en - st + 3) & ~3);
    int j = st;
    for (; j + 8 <= en_pad; j += 8) {
        int4   sa = *(const int4*)  &csr_src[j];
        int4   sb = *(const int4*)  &csr_src[j + 4];
        float4 na = *(const float4*)&csr_nrm[j];
        float4 nb = *(const float4*)&csr_nrm[j + 4];
        uint4 r0 = *(const uint4*)&Hl[(size_t)sa.x * 64];
        uint4 r1 = *(const uint4*)&Hl[(size_t)sa.y * 64];
        uint4 r2 = *(const uint4*)&Hl[(size_t)sa.z * 64];
        uint4 r3 = *(const uint4*)&Hl[(size_t)sa.w * 64];
        uint4 r4 = *(const uint4*)&Hl[(size_t)sb.x * 64];
        uint4 r5 = *(const uint4*)&Hl[(size_t)sb.y * 64];
        uint4 r6 = *(const uint4*)&Hl[(size_t)sb.z * 64];
        uint4 r7 = *(const uint4*)&Hl[(size_t)sb.w * 64];
        accum8(acc, r0, na.x);  accum8(acc, r1, na.y);
        accum8(acc, r2, na.z);  accum8(acc, r3, na.w);
        accum8(acc, r4, nb.x);  accum8(acc, r5, nb.y);
        accum8(acc, r6, nb.z);  accum8(acc, r7, nb.w);
    }
    if (j < en_pad) {
        int4   sa = *(const int4*)  &csr_src[j];
        float4 na = *(const float4*)&csr_nrm[j];
        uint4 r0 = *(const uint4*)&Hl[(size_t)sa.x * 64];
        uint4 r1 = *(const uint4*)&Hl[(size_t)sa.y * 64];
        uint4 r2 = *(const uint4*)&Hl[(size_t)sa.z * 64];
        uint4 r3 = *(const uint4*)&Hl[(size_t)sa.w * 64];
        accum8(acc, r0, na.x);  accum8(acc, r1, na.y);
        accum8(acc, r2, na.z);  accum8(acc, r3, na.w);
    }
    // self-loop
    float di = dinv[node];
    uint4 rs = *(const uint4*)&Hl[(size_t)node * 64];
    accum8(acc, rs, di * di);
}

// ============== gather1 + GEMM2 fused ==============
// Per block: 16 nodes gathered (agg1 in regs) -> LDS fp32 -> relu(+b1) @ W2
// (bf16, staged in LDS once per block) -> write h2 bf16 to O.
__global__ __launch_bounds__(256) void gather_gemm(
    const u32* __restrict__ H, u32* __restrict__ O,
    const int* __restrict__ csr_src, const float* __restrict__ csr_nrm,
    const int* __restrict__ start, const int* __restrict__ end_,
    const float* __restrict__ dinv, int N,
    const float* __restrict__ b1, const float* __restrict__ W2)
{
    __shared__ ushort Ws[DIM][136];     // bf16 W2, padded
    __shared__ float  accs[16][132];    // fp32 agg1 rows, padded

    const int t    = threadIdx.x;
    const int grp  = t >> 4;            // 0..15 node within block
    const int gl   = t & 15;            // lane within group
    const int node = blockIdx.x * 16 + grp;
    const bool valid = node < N;

    // stage W2 -> bf16 LDS (all threads; 16 float4 iters)
    for (int idx = t; idx < DIM * DIM / 4; idx += 256) {
        float4 wv = *(const float4*)&W2[idx * 4];
        int r = (idx * 4) >> 7, c = (idx * 4) & 127;
        Ws[r][c]     = bf16_of(wv.x);
        Ws[r][c + 1] = bf16_of(wv.y);
        Ws[r][c + 2] = bf16_of(wv.z);
        Ws[r][c + 3] = bf16_of(wv.w);
    }

    float acc[8] = {0.f,0.f,0.f,0.f,0.f,0.f,0.f,0.f};
    if (valid) {
        const u32* Hl = H + gl * 4;
        gather_core(Hl, csr_src, csr_nrm, dinv, node, start[node], end_[node], acc);
    }

    // relu(agg1 + b1) -> LDS (fp32: no intermediate bf16 rounding)
    {
        int f0 = gl * 8;
        float4 bA = *(const float4*)&b1[f0];
        float4 bB = *(const float4*)&b1[f0 + 4];
        float bb[8] = {bA.x,bA.y,bA.z,bA.w,bB.x,bB.y,bB.z,bB.w};
        #pragma unroll
        for (int i = 0; i < 8; ++i)
            accs[grp][f0 + i] = fmaxf(acc[i] + bb[i], 0.f);
    }
    __syncthreads();

    // GEMM: h2[node][f] = sum_k accs[node][k] * W2[k][f]
    // thread t: node = t>>4, feats fb..fb+7 (fb=(t&15)*8)
    {
        const int n  = t >> 4;
        const int fb = (t & 15) * 8;
        float o[8] = {0.f,0.f,0.f,0.f,0.f,0.f,0.f,0.f};
        #pragma unroll 4
        for (int k = 0; k < DIM; ++k) {
            float a = accs[n][k];                     // broadcast within group
            const ushort* wr = &Ws[k][fb];            // 16 B -> ds_read_b128
            ushort4 w0 = *(const ushort4*)wr;
            ushort4 w1 = *(const ushort4*)(wr + 4);
            o[0] = fmaf(a, f_of_bf16(w0.x), o[0]);
            o[1] = fmaf(a, f_of_bf16(w0.y), o[1]);
            o[2] = fmaf(a, f_of_bf16(w0.z), o[2]);
            o[3] = fmaf(a, f_of_bf16(w0.w), o[3]);
            o[4] = fmaf(a, f_of_bf16(w1.x), o[4]);
            o[5] = fmaf(a, f_of_bf16(w1.y), o[5]);
            o[6] = fmaf(a, f_of_bf16(w1.z), o[6]);
            o[7] = fmaf(a, f_of_bf16(w1.w), o[7]);
        }
        int onode = blockIdx.x * 16 + n;
        if (onode < N) {
            uint4 ov;
            ov.x = pack_bf16x2(o[0], o[1]);
            ov.y = pack_bf16x2(o[2], o[3]);
            ov.z = pack_bf16x2(o[4], o[5]);
            ov.w = pack_bf16x2(o[6], o[7]);
            *(uint4*)&O[(size_t)onode * 64 + (t & 15) * 4] = ov;
        }
    }
}

// ============== gather2 + pool fused (r9-verified) ==============
__global__ __launch_bounds__(256) void gather_pool(
    const u32* __restrict__ H,
    const int* __restrict__ csr_src, const float* __restrict__ csr_nrm,
    const int* __restrict__ start, const int* __restrict__ end_,
    const float* __restrict__ dinv, int N,
    const float* __restrict__ b2, const float* __restrict__ wlin,
    const int* __restrict__ batch, float* __restrict__ sums, float* __restrict__ cnt)
{
    const int grp  = threadIdx.x >> 4;
    const int gl   = threadIdx.x & 15;
    const int node = blockIdx.x * 16 + grp;
    if (node >= N) return;

    float acc[8] = {0.f,0.f,0.f,0.f,0.f,0.f,0.f,0.f};
    const u32* Hl = H + gl * 4;
    gather_core(Hl, csr_src, csr_nrm, dinv, node, start[node], end_[node], acc);

    int f0 = gl * 8;
    float v = 0.f;
    #pragma unroll
    for (int i = 0; i < 8; ++i)
        v += fmaxf(acc[i] + b2[f0 + i], 0.f) * wlin[f0 + i];
    #pragma unroll
    for (int m = 1; m <= 8; m <<= 1) v += __shfl_xor(v, m, 64);
    if (gl == 0) {
        int g = batch[node];
        unsafeAtomicAdd(&sums[g], v);
        unsafeAtomicAdd(&cnt[g], 1.0f);
    }
}

__global__ void final_kernel(const float* __restrict__ sums,
                             const float* __restrict__ cnt,
                             const float* __restrict__ blin,
                             float* __restrict__ out, int G)
{
    int g = blockIdx.x * blockDim.x + threadIdx.x;
    if (g < G) out[g] = sums[g] / fmaxf(cnt[g], 1.0f) + blin[0];
}

// ======================= launch =======================

extern "C" void kernel_launch(void* const* d_in, const int* in_sizes, int n_in,
                              void* d_out, int out_size, void* d_ws, size_t ws_size,
                              hipStream_t stream)
{
    const float* x    = (const float*)d_in[0];
    const int*   src  = (const int*)d_in[1];
    const int*   dst  = (const int*)d_in[2];
    const int*   batch= (const int*)d_in[3];
    const float* W1   = (const float*)d_in[5];
    const float* b1   = (const float*)d_in[6];
    const float* W2   = (const float*)d_in[7];
    const float* b2   = (const float*)d_in[8];
    const float* wlin = (const float*)d_in[9];
    const float* blin = (const float*)d_in[10];
    float* out = (float*)d_out;

    const int N = in_sizes[0] / DIM;
    const int E = in_sizes[1];
    const int G = out_size;
    const size_t E_pad = (size_t)E + 4 * (size_t)N;   // per-bucket pad to x4

    u32*   B0    = (u32*)d_ws;
    u32*   B1    = B0 + (size_t)N * 64;
    float* dinv  = (float*)(B1 + (size_t)N * 64);
    float* sums  = dinv + N;
    float* cnt   = sums + G;
    int*   deg_c = (int*)(cnt + G);
    int*   start = deg_c + N;
    int*   end_  = start + N;
    int*   csrs  = end_ + N;
    float* csrn  = (float*)(csrs + E_pad);
    int*   total = (int*)(csrn + E_pad);
    size_t need_bytes = ((size_t)(total + 1) - (size_t)d_ws);
    if (ws_size < need_bytes) return;

    const int gblocks = (N + 63) / 64;
    const int eblocks = (E + 255) / 256;
    const int g4blocks = (N + 15) / 16;

    // ---- init, then gemm1 fused with edge_count ----
    init_k<<<(N + 255) / 256, 256, 0, stream>>>(deg_c, total, sums, cnt, N, G);
    gemm1_count<<<gblocks + eblocks, 256, 0, stream>>>(x, W1, B0, N, gblocks,
                                                       deg_c, dst, E);
    alloc_offsets<<<(N + 255) / 256, 256, 0, stream>>>(deg_c, start, end_, deg_c,
                                                       dinv, total, csrs, csrn, N);
    scatter_edges<<<eblocks, 256, 0, stream>>>(src, dst, dinv, deg_c, csrs, csrn, E);

    // ---- layer 1 aggregation + layer 2 GEMM (fused) ----
    gather_gemm<<<g4blocks, 256, 0, stream>>>(B0, B1, csrs, csrn, start, end_,
                                              dinv, N, b1, W2);
    // ---- layer 2 aggregation + pooling (fused) ----
    gather_pool<<<g4blocks, 256, 0, stream>>>(B1, csrs, csrn, start, end_,
                                              dinv, N, b2, wlin, batch, sums, cnt);
    final_kernel<<<(G + 255) / 256, 256, 0, stream>>>(sums, cnt, blin, out, G);
}

// Round 14
// 310.104 us; speedup vs baseline: 7.0143x; 1.0429x over previous
//
#include <hip/hip_runtime.h>
#include <hip/hip_bf16.h>

#define DIM 128
typedef unsigned int u32;

// bf16x2 pack/unpack: low ushort = even feature, high = odd feature.
__device__ __forceinline__ u32 pack_bf16x2(float a, float b) {
    u32 ua = __float_as_uint(a), ub = __float_as_uint(b);
    ua = (ua + 0x7FFFu + ((ua >> 16) & 1u)) >> 16;        // RNE
    ub = (ub + 0x7FFFu + ((ub >> 16) & 1u)) >> 16;
    return ua | (ub << 16);
}
__device__ __forceinline__ ushort bf16_of(float a) {
    u32 ua = __float_as_uint(a);
    return (ushort)((ua + 0x7FFFu + ((ua >> 16) & 1u)) >> 16);
}
__device__ __forceinline__ float f_of_bf16(ushort h) {
    return __uint_as_float(((u32)h) << 16);
}
__device__ __forceinline__ float2 unpack_bf16x2(u32 h) {
    return make_float2(__uint_as_float(h << 16), __uint_as_float(h & 0xFFFF0000u));
}

__device__ __forceinline__ void accum8(float* acc, uint4 r, float n) {
    float2 p0 = unpack_bf16x2(r.x), p1 = unpack_bf16x2(r.y);
    float2 p2 = unpack_bf16x2(r.z), p3 = unpack_bf16x2(r.w);
    acc[0] = fmaf(p0.x, n, acc[0]); acc[1] = fmaf(p0.y, n, acc[1]);
    acc[2] = fmaf(p1.x, n, acc[2]); acc[3] = fmaf(p1.y, n, acc[3]);
    acc[4] = fmaf(p2.x, n, acc[4]); acc[5] = fmaf(p2.y, n, acc[5]);
    acc[6] = fmaf(p3.x, n, acc[6]); acc[7] = fmaf(p3.y, n, acc[7]);
}

// ======================= init =======================
__global__ void init_k(int* __restrict__ deg, int* __restrict__ total,
                       float* __restrict__ sums, float* __restrict__ cnt,
                       int N, int G)
{
    int i = blockIdx.x * blockDim.x + threadIdx.x;
    if (i < N) deg[i] = 0;
    if (i == 0) *total = 0;
    if (i < G) { sums[i] = 0.f; cnt[i] = 0.f; }
}

__global__ void edge_count(int* __restrict__ deg, const int* __restrict__ dst, int E) {
    int e = blockIdx.x * blockDim.x + threadIdx.x;
    if (e < E) atomicAdd(&deg[dst[e]], 1);
}

// ======================= CSR offsets =======================
// Buckets padded to x4; pad slots zeroed here (nrm=0 contributes nothing).
// endp[i] = padded end -> gather range [start[i], endp[i]) is a multiple of 4.
// NOTE: bucket placement across waves is nondeterministic (per-wave atomicAdd
// base), so per-node end must be stored explicitly — start[i+1] is NOT valid.
__global__ __launch_bounds__(256) void alloc_offsets(
    const int* __restrict__ deg, int* __restrict__ start, int* __restrict__ endp,
    int* __restrict__ cursor, float* __restrict__ dinv, int* __restrict__ total,
    uint2* __restrict__ csr, int N)
{
    int i = blockIdx.x * blockDim.x + threadIdx.x;
    int lane = threadIdx.x & 63;
    int d  = (i < N) ? deg[i] : 0;
    int d4 = (d + 3) & ~3;
    int pre = d4;
    #pragma unroll
    for (int off = 1; off < 64; off <<= 1) {
        int v = __shfl_up(pre, off, 64);
        if (lane >= off) pre += v;
    }
    int waveTot = __shfl(pre, 63, 64);
    int base = 0;
    if (lane == 63) base = atomicAdd(total, waveTot);
    base = __shfl(base, 63, 64);
    if (i < N) {
        int st = base + pre - d4;
        start[i]  = st;
        endp[i]   = st + d4;
        cursor[i] = st;
        dinv[i]   = rsqrtf((float)(d + 1));   // +1 self-loop
        for (int p = d; p < d4; ++p)          // zero the <=3 pad slots
            csr[st + p] = make_uint2(0u, 0u);
    }
}

// ======================= GEMM1 body =======================
// Y[node][f] = sum_k X[node][k] * W[k][f]; X fp32, W fp32, Y bf16.
__device__ __forceinline__ void gemm_body0(
    const float* __restrict__ X, const float* __restrict__ W,
    u32* __restrict__ Y, int N, int block)
{
    __shared__ float As[32][72];
    __shared__ float Bs[32][132];
    const int t = threadIdx.x;
    const int node0 = block * 64;
    const int tx = t & 31;
    const int ty = t >> 5;
    const int f0 = tx * 4;
    const int n0 = ty * 8;

    float acc[8][4];
    #pragma unroll
    for (int i = 0; i < 8; ++i)
        #pragma unroll
        for (int j = 0; j < 4; ++j) acc[i][j] = 0.f;

    const int sr  = t >> 3;
    const int sc4 = (t & 7) * 4;

    for (int k0 = 0; k0 < DIM; k0 += 32) {
        #pragma unroll
        for (int half = 0; half < 2; ++half) {
            int r = sr + half * 32;
            int node = node0 + r;
            float v[4] = {0.f, 0.f, 0.f, 0.f};
            if (node < N)
                *(float4*)v = *(const float4*)&X[(size_t)node * DIM + k0 + sc4];
            #pragma unroll
            for (int i = 0; i < 4; ++i) As[sc4 + i][r] = v[i];
        }
        #pragma unroll
        for (int i = 0; i < 4; ++i) {
            int kk = (t >> 5) + i * 8;
            float4 wv = *(const float4*)&W[(size_t)(k0 + kk) * DIM + f0];
            *(float4*)&Bs[kk][f0] = wv;
        }
        __syncthreads();

        #pragma unroll 4
        for (int kk = 0; kk < 32; ++kk) {
            float4 a0 = *(const float4*)&As[kk][n0];
            float4 a1 = *(const float4*)&As[kk][n0 + 4];
            float4 b  = *(const float4*)&Bs[kk][f0];
            float av[8] = {a0.x,a0.y,a0.z,a0.w,a1.x,a1.y,a1.z,a1.w};
            float bv[4] = {b.x,b.y,b.z,b.w};
            #pragma unroll
            for (int i = 0; i < 8; ++i)
                #pragma unroll
                for (int j = 0; j < 4; ++j)
                    acc[i][j] = fmaf(av[i], bv[j], acc[i][j]);
        }
        __syncthreads();
    }

    #pragma unroll
    for (int i = 0; i < 8; ++i) {
        int node = node0 + n0 + i;
        if (node < N) {
            uint2 o;
            o.x = pack_bf16x2(acc[i][0], acc[i][1]);
            o.y = pack_bf16x2(acc[i][2], acc[i][3]);
            *(uint2*)&Y[(size_t)node * 64 + f0 / 2] = o;
        }
    }
}

// Fused: blocks [0,gblocks) run gemm1; the rest scatter edges into CSR.
__global__ __launch_bounds__(256) void scatter_gemm1(
    const float* __restrict__ x, const float* __restrict__ W1,
    u32* __restrict__ Y, int N, int gblocks,
    const int* __restrict__ src, const int* __restrict__ dst,
    const float* __restrict__ dinv, int* __restrict__ cursor,
    uint2* __restrict__ csr, int E)
{
    if ((int)blockIdx.x < gblocks) {
        gemm_body0(x, W1, Y, N, blockIdx.x);
    } else {
        int e = ((int)blockIdx.x - gblocks) * 256 + threadIdx.x;
        if (e < E) {
            int s = src[e], d = dst[e];
            int p = atomicAdd(&cursor[d], 1);
            csr[p] = make_uint2((u32)s, __float_as_uint(dinv[s] * dinv[d]));
        }
    }
}

// ======================= gather core (4 nodes / wave) =====================
// 16 lanes per node; lane gl holds dwords 4gl..4gl+3 (features 8gl..8gl+7).
// Metadata: interleaved (src,nrm) uint2 records, 2 edges per uint4 load.
// Range [st, en_pad) is a multiple of 4 (pads contribute 0).
__device__ __forceinline__ void gather_core(
    const u32* __restrict__ Hl, const uint2* __restrict__ csr,
    const float* __restrict__ dinv, int node, int st, int en_pad, float* acc)
{
    int j = st;
    for (; j + 8 <= en_pad; j += 8) {
        uint4 m0 = *(const uint4*)&csr[j];
        uint4 m1 = *(const uint4*)&csr[j + 2];
        uint4 m2 = *(const uint4*)&csr[j + 4];
        uint4 m3 = *(const uint4*)&csr[j + 6];
        uint4 r0 = *(const uint4*)&Hl[(size_t)m0.x * 64];
        uint4 r1 = *(const uint4*)&Hl[(size_t)m0.z * 64];
        uint4 r2 = *(const uint4*)&Hl[(size_t)m1.x * 64];
        uint4 r3 = *(const uint4*)&Hl[(size_t)m1.z * 64];
        uint4 r4 = *(const uint4*)&Hl[(size_t)m2.x * 64];
        uint4 r5 = *(const uint4*)&Hl[(size_t)m2.z * 64];
        uint4 r6 = *(const uint4*)&Hl[(size_t)m3.x * 64];
        uint4 r7 = *(const uint4*)&Hl[(size_t)m3.z * 64];
        accum8(acc, r0, __uint_as_float(m0.y));
        accum8(acc, r1, __uint_as_float(m0.w));
        accum8(acc, r2, __uint_as_float(m1.y));
        accum8(acc, r3, __uint_as_float(m1.w));
        accum8(acc, r4, __uint_as_float(m2.y));
        accum8(acc, r5, __uint_as_float(m2.w));
        accum8(acc, r6, __uint_as_float(m3.y));
        accum8(acc, r7, __uint_as_float(m3.w));
    }
    if (j < en_pad) {   // exactly one 4-chunk
        uint4 m0 = *(const uint4*)&csr[j];
        uint4 m1 = *(const uint4*)&csr[j + 2];
        uint4 r0 = *(const uint4*)&Hl[(size_t)m0.x * 64];
        uint4 r1 = *(const uint4*)&Hl[(size_t)m0.z * 64];
        uint4 r2 = *(const uint4*)&Hl[(size_t)m1.x * 64];
        uint4 r3 = *(const uint4*)&Hl[(size_t)m1.z * 64];
        accum8(acc, r0, __uint_as_float(m0.y));
        accum8(acc, r1, __uint_as_float(m0.w));
        accum8(acc, r2, __uint_as_float(m1.y));
        accum8(acc, r3, __uint_as_float(m1.w));
    }
    // self-loop
    float di = dinv[node];
    uint4 rs = *(const uint4*)&Hl[(size_t)node * 64];
    accum8(acc, rs, di * di);
}

// ============== gather1 + GEMM2 fused ==============
__global__ __launch_bounds__(256) void gather_gemm(
    const u32* __restrict__ H, u32* __restrict__ O,
    const uint2* __restrict__ csr, const int* __restrict__ start,
    const int* __restrict__ endp, const float* __restrict__ dinv, int N,
    const float* __restrict__ b1, const float* __restrict__ W2)
{
    __shared__ ushort Ws[DIM][136];     // bf16 W2, padded
    __shared__ float  accs[16][132];    // fp32 agg1 rows, padded

    const int t    = threadIdx.x;
    const int grp  = t >> 4;
    const int gl   = t & 15;
    const int node = blockIdx.x * 16 + grp;
    const bool valid = node < N;

    for (int idx = t; idx < DIM * DIM / 4; idx += 256) {
        float4 wv = *(const float4*)&W2[idx * 4];
        int r = (idx * 4) >> 7, c = (idx * 4) & 127;
        Ws[r][c]     = bf16_of(wv.x);
        Ws[r][c + 1] = bf16_of(wv.y);
        Ws[r][c + 2] = bf16_of(wv.z);
        Ws[r][c + 3] = bf16_of(wv.w);
    }

    float acc[8] = {0.f,0.f,0.f,0.f,0.f,0.f,0.f,0.f};
    if (valid) {
        const u32* Hl = H + gl * 4;
        gather_core(Hl, csr, dinv, node, start[node], endp[node], acc);
    }

    {
        int f0 = gl * 8;
        float4 bA = *(const float4*)&b1[f0];
        float4 bB = *(const float4*)&b1[f0 + 4];
        float bb[8] = {bA.x,bA.y,bA.z,bA.w,bB.x,bB.y,bB.z,bB.w};
        #pragma unroll
        for (int i = 0; i < 8; ++i)
            accs[grp][f0 + i] = fmaxf(acc[i] + bb[i], 0.f);
    }
    __syncthreads();

    {
        const int n  = t >> 4;
        const int fb = (t & 15) * 8;
        float o[8] = {0.f,0.f,0.f,0.f,0.f,0.f,0.f,0.f};
        #pragma unroll 4
        for (int k = 0; k < DIM; ++k) {
            float a = accs[n][k];
            const ushort* wr = &Ws[k][fb];
            ushort4 w0 = *(const ushort4*)wr;
            ushort4 w1 = *(const ushort4*)(wr + 4);
            o[0] = fmaf(a, f_of_bf16(w0.x), o[0]);
            o[1] = fmaf(a, f_of_bf16(w0.y), o[1]);
            o[2] = fmaf(a, f_of_bf16(w0.z), o[2]);
            o[3] = fmaf(a, f_of_bf16(w0.w), o[3]);
            o[4] = fmaf(a, f_of_bf16(w1.x), o[4]);
            o[5] = fmaf(a, f_of_bf16(w1.y), o[5]);
            o[6] = fmaf(a, f_of_bf16(w1.z), o[6]);
            o[7] = fmaf(a, f_of_bf16(w1.w), o[7]);
        }
        int onode = blockIdx.x * 16 + n;
        if (onode < N) {
            uint4 ov;
            ov.x = pack_bf16x2(o[0], o[1]);
            ov.y = pack_bf16x2(o[2], o[3]);
            ov.z = pack_bf16x2(o[4], o[5]);
            ov.w = pack_bf16x2(o[6], o[7]);
            *(uint4*)&O[(size_t)onode * 64 + (t & 15) * 4] = ov;
        }
    }
}

// ============== gather2 + pool fused ==============
__global__ __launch_bounds__(256) void gather_pool(
    const u32* __restrict__ H,
    const uint2* __restrict__ csr, const int* __restrict__ start,
    const int* __restrict__ endp, const float* __restrict__ dinv, int N,
    const float* __restrict__ b2, const float* __restrict__ wlin,
    const int* __restrict__ batch, float* __restrict__ sums, float* __restrict__ cnt)
{
    const int grp  = threadIdx.x >> 4;
    const int gl   = threadIdx.x & 15;
    const int node = blockIdx.x * 16 + grp;
    if (node >= N) return;

    float acc[8] = {0.f,0.f,0.f,0.f,0.f,0.f,0.f,0.f};
    const u32* Hl = H + gl * 4;
    gather_core(Hl, csr, dinv, node, start[node], endp[node], acc);

    int f0 = gl * 8;
    float v = 0.f;
    #pragma unroll
    for (int i = 0; i < 8; ++i)
        v += fmaxf(acc[i] + b2[f0 + i], 0.f) * wlin[f0 + i];
    #pragma unroll
    for (int m = 1; m <= 8; m <<= 1) v += __shfl_xor(v, m, 64);
    if (gl == 0) {
        int g = batch[node];
        unsafeAtomicAdd(&sums[g], v);
        unsafeAtomicAdd(&cnt[g], 1.0f);
    }
}

__global__ void final_kernel(const float* __restrict__ sums,
                             const float* __restrict__ cnt,
                             const float* __restrict__ blin,
                             float* __restrict__ out, int G)
{
    int g = blockIdx.x * blockDim.x + threadIdx.x;
    if (g < G) out[g] = sums[g] / fmaxf(cnt[g], 1.0f) + blin[0];
}

// ======================= launch =======================

extern "C" void kernel_launch(void* const* d_in, const int* in_sizes, int n_in,
                              void* d_out, int out_size, void* d_ws, size_t ws_size,
                              hipStream_t stream)
{
    const float* x    = (const float*)d_in[0];
    const int*   src  = (const int*)d_in[1];
    const int*   dst  = (const int*)d_in[2];
    const int*   batch= (const int*)d_in[3];
    const float* W1   = (const float*)d_in[5];
    const float* b1   = (const float*)d_in[6];
    const float* W2   = (const float*)d_in[7];
    const float* b2   = (const float*)d_in[8];
    const float* wlin = (const float*)d_in[9];
    const float* blin = (const float*)d_in[10];
    float* out = (float*)d_out;

    const int N = in_sizes[0] / DIM;
    const int E = in_sizes[1];
    const int G = out_size;
    const size_t E_pad = (size_t)E + 4 * (size_t)N;   // per-bucket pad to x4

    // layout: B0(bf16 N*64 u32), B1, dinv(N), sums(G), cnt(G),
    //         deg/cursor(N), start(N), endp(N), csr(uint2 E_pad), total
    u32*   B0    = (u32*)d_ws;
    u32*   B1    = B0 + (size_t)N * 64;
    float* dinv  = (float*)(B1 + (size_t)N * 64);
    float* sums  = dinv + N;
    float* cnt   = sums + G;
    int*   deg_c = (int*)(cnt + G);
    int*   start = deg_c + N;
    int*   endp  = start + N;
    uint2* csr   = (uint2*)(endp + N);
    int*   total = (int*)(csr + E_pad);
    size_t need_bytes = ((size_t)(total + 1) - (size_t)d_ws);
    if (ws_size < need_bytes) return;

    const int gblocks = (N + 63) / 64;
    const int eblocks = (E + 255) / 256;
    const int g4blocks = (N + 15) / 16;

    init_k<<<(N + 255) / 256, 256, 0, stream>>>(deg_c, total, sums, cnt, N, G);
    edge_count<<<eblocks, 256, 0, stream>>>(deg_c, dst, E);
    alloc_offsets<<<(N + 255) / 256, 256, 0, stream>>>(deg_c, start, endp, deg_c,
                                                       dinv, total, csr, N);
    // gemm1 fused with edge scatter (independent work)
    scatter_gemm1<<<gblocks + eblocks, 256, 0, stream>>>(x, W1, B0, N, gblocks,
                                                         src, dst, dinv, deg_c,
                                                         csr, E);
    // layer 1 aggregation + layer 2 GEMM (fused)
    gather_gemm<<<g4blocks, 256, 0, stream>>>(B0, B1, csr, start, endp, dinv,
                                              N, b1, W2);
    // layer 2 aggregation + pooling (fused)
    gather_pool<<<g4blocks, 256, 0, stream>>>(B1, csr, start, endp, dinv, N,
                                              b2, wlin, batch, sums, cnt);
    final_kernel<<<(G + 255) / 256, 256, 0, stream>>>(sums, cnt, blin, out, G);
}